// Round 6
// baseline (496.700 us; speedup 1.0000x reference)
//
#include <hip/hip_runtime.h>
#include <hip/hip_bf16.h>

// MHGCN: out = 0.5*(U1+U2), U1 = S@(feat@W1)+b1, U2 = S@(U1@W2)+b2,
// S = temp + temp^T (symmetric), temp = einsum('ijk,kl->ij', A_stack, weight_b)
// N=8192, NFEAT=OUT=64.
//
//  1) k_sym_build: A_stack (1.34 GB, read once, FULLY-COALESCED dwordx4 via
//     LDS bounce — each 64B line touched exactly once). R4 bug fixed: output
//     phases now cover all 64 rows (was 32 -> half-poisoned S).
//  2) k_small_gemm_t: feature@W1 -> H1t bf16 [64][N]
//  3) k_gemm_skinny<0>: U1 = S@H1 + b1 — global_load_lds dbuf MFMA (as R3)
//  4) k_small_gemm_t: U1@W2 -> H2t
//  5) k_gemm_skinny<1>: out = 0.5*(U1 + S@H2 + b2)

#define NN 8192

typedef __attribute__((ext_vector_type(8))) short short8;
typedef __attribute__((ext_vector_type(8))) unsigned short u16x8;
typedef __attribute__((ext_vector_type(4))) unsigned short u16x4;
typedef __attribute__((ext_vector_type(4))) float f32x4;

static __device__ __forceinline__ unsigned short f2bf(float f) {
    unsigned u = __float_as_uint(f);
    u += 0x7FFFu + ((u >> 16) & 1u);     // round-to-nearest-even
    return (unsigned short)(u >> 16);
}

#define GL16(gsrc, ldst) __builtin_amdgcn_global_load_lds( \
    (const __attribute__((address_space(1))) void*)(gsrc), \
    (__attribute__((address_space(3))) void*)(ldst), 16, 0, 0)

// ---------------------------------------------------------------------------
// 1) S = temp + temp^T (bf16). Upper-tri 64x64 tile pairs; A read exactly once,
//    every 64B line touched exactly once (dense dwordx4 + per-wave LDS bounce).
//    Per tile row (320 f32 = 80 chunks): lane c loads chunk c (0..63), lanes
//    0..15 load chunks 64..79; raw -> LDS; s_waitcnt lgkmcnt(0); lane j reads
//    raw[5j..5j+4] and FMAs. temp1 row-major (T1s), temp2 transposed (T2t).
// ---------------------------------------------------------------------------
__global__ __launch_bounds__(256) void k_sym_build(
        const float* __restrict__ A, const float* __restrict__ wb,
        unsigned short* __restrict__ S) {
    __shared__ float raw[4][336];       // per-wave row bounce (320 used)
    __shared__ float T1s[64 * 65];      // temp1 row-major, padded
    __shared__ float T2t[64 * 65];      // temp2 transposed,  padded

    int b = blockIdx.x;
    // decode linear id -> (bi, bj), bi <= bj, 128x128 tiles
    double disc = 66049.0 - 8.0 * (double)b;
    int bi = (int)((257.0 - sqrt(disc)) * 0.5);
    if (bi < 0) bi = 0; if (bi > 127) bi = 127;
    while (bi < 127 && (bi + 1) * (257 - (bi + 1)) / 2 <= b) ++bi;
    while (bi > 0 && bi * (257 - bi) / 2 > b) --bi;
    int bj = bi + (b - bi * (257 - bi) / 2);

    const float w0 = wb[0], w1 = wb[1], w2 = wb[2], w3 = wb[3], w4 = wb[4];
    int t = threadIdx.x, lane = t & 63, w = t >> 6;

    #pragma unroll
    for (int half = 0; half < 2; ++half) {
        int tr = half == 0 ? bi : bj;        // tile row-base (in A)
        int tc = half == 0 ? bj : bi;        // tile col-base
        for (int rr = 0; rr < 16; ++rr) {
            int r = rr * 4 + w;              // row of this tile handled by wave w
            const f32x4* rowp = (const f32x4*)(A +
                ((long long)(tr * 64 + r) * NN + tc * 64) * 5);   // 1280B, 16B-aligned
            f32x4 c0 = rowp[lane];                       // chunks 0..63 (dense)
            f32x4 c1;
            if (lane < 16) c1 = rowp[64 + lane];         // chunks 64..79
            *(f32x4*)&raw[w][lane * 4] = c0;
            if (lane < 16) *(f32x4*)&raw[w][256 + lane * 4] = c1;
            asm volatile("s_waitcnt lgkmcnt(0)" ::: "memory");  // writes visible
            float a0 = raw[w][5 * lane + 0];
            float a1 = raw[w][5 * lane + 1];
            float a2 = raw[w][5 * lane + 2];
            float a3 = raw[w][5 * lane + 3];
            float a4 = raw[w][5 * lane + 4];
            float tv = a0 * w0 + a1 * w1 + a2 * w2 + a3 * w3 + a4 * w4;
            __builtin_amdgcn_wave_barrier();             // pin order vs next iter
            if (half == 0) T1s[r * 65 + lane] = tv;      // row-major
            else           T2t[lane * 65 + r] = tv;      // transposed write
        }
    }
    __syncthreads();

    // Phase B: main tile  S[bi-tile][bj-tile][i][j] = T1s[i][j] + T2t[i][j]
    #pragma unroll
    for (int e = 0; e < 2; ++e) {
        int i = (t >> 3) + 32 * e;
        int j0 = (t & 7) * 8;
        u16x8 o;
        #pragma unroll
        for (int q = 0; q < 8; ++q)
            o[q] = f2bf(T1s[i * 65 + j0 + q] + T2t[i * 65 + j0 + q]);
        *(u16x8*)(S + (long long)(bi * 64 + i) * NN + bj * 64 + j0) = o;
    }
    // Phase C: mirror tile S[bj-tile][bi-tile][i][j] = tile[j][i]
    if (bi != bj) {
        #pragma unroll
        for (int e = 0; e < 2; ++e) {
            int i = (t >> 3) + 32 * e;
            int j0 = (t & 7) * 8;
            u16x8 o;
            #pragma unroll
            for (int q = 0; q < 8; ++q)
                o[q] = f2bf(T1s[(j0 + q) * 65 + i] + T2t[(j0 + q) * 65 + i]);
            *(u16x8*)(S + (long long)(bj * 64 + i) * NN + bi * 64 + j0) = o;
        }
    }
}

// ---------------------------------------------------------------------------
// 2/4) Yt[c][row] = sum_k X[row][k]*W[k][c]   (bf16, transposed output)
// ---------------------------------------------------------------------------
__global__ __launch_bounds__(256) void k_small_gemm_t(
        const float* __restrict__ X, const float* __restrict__ W,
        unsigned short* __restrict__ Yt) {
    __shared__ float Ys[64 * 65];
    int t = threadIdx.x, lane = t & 63, w = t >> 6;
    float wcol[64];
    #pragma unroll
    for (int k = 0; k < 64; ++k) wcol[k] = W[k * 64 + lane];
    int r0 = blockIdx.x * 64;
    for (int rr = 0; rr < 16; ++rr) {
        const f32x4* x = (const f32x4*)(X + (long long)(r0 + w * 16 + rr) * 64);
        float acc = 0.f;
        #pragma unroll
        for (int k4 = 0; k4 < 16; ++k4) {
            f32x4 xv = x[k4];
            acc += xv[0]*wcol[4*k4] + xv[1]*wcol[4*k4+1]
                 + xv[2]*wcol[4*k4+2] + xv[3]*wcol[4*k4+3];
        }
        Ys[lane * 65 + w * 16 + rr] = acc;    // Ys[col][row-in-tile]
    }
    __syncthreads();
    int c = t >> 2, j0 = (t & 3) * 16;
    u16x8 o0, o1;
    #pragma unroll
    for (int q = 0; q < 8; ++q) {
        o0[q] = f2bf(Ys[c * 65 + j0 + q]);
        o1[q] = f2bf(Ys[c * 65 + j0 + 8 + q]);
    }
    *(u16x8*)(Yt + (long long)c * NN + r0 + j0) = o0;
    *(u16x8*)(Yt + (long long)c * NN + r0 + j0 + 8) = o1;
}

// ---------------------------------------------------------------------------
// 3/5) Y[i][f] = (FINAL? 0.5*(U1+.) : .)(bias[f] + sum_j S[i][j]*H[j][f])
//   global_load_lds (width 16) double-buffered staging; linear LDS dest with
//   pre-swizzled GLOBAL source so ds_read_b128 is XOR-bank-spread.
// ---------------------------------------------------------------------------
template<int FINAL>
__global__ __launch_bounds__(256) void k_gemm_skinny(
        const unsigned short* __restrict__ S,
        const unsigned short* __restrict__ Ht,   // [64][NN]
        const float* __restrict__ bias,
        const float* __restrict__ U1,
        float* __restrict__ Y) {
    __shared__ unsigned short Ts[2][16 * 128];   // 2 x 4 KB
    __shared__ unsigned short Hs[2][64 * 128];   // 2 x 16 KB
    int t = threadIdx.x, lane = t & 63, w = t >> 6;
    int i0 = blockIdx.x * 16;
    int r = lane & 15, kg = lane >> 4;

    int srow = t >> 4, sc = t & 15;
    int sbyte = (sc * 16) ^ ((srow & 7) << 4);          // byte within 256B row seg
    const unsigned short* aSrc = S + (long long)(i0 + srow) * NN + (sbyte >> 1);
    const unsigned short* hSrc = Ht + (long long)srow * NN + (sbyte >> 1);
    char* tsDst0 = (char*)&Ts[0][0] + t * 16;
    char* tsDst1 = (char*)&Ts[1][0] + t * 16;
    char* hsDst0 = (char*)&Hs[0][0] + t * 16;
    char* hsDst1 = (char*)&Hs[1][0] + t * 16;

    f32x4 acc = {0.f, 0.f, 0.f, 0.f};

    GL16(aSrc, tsDst0);
    #pragma unroll
    for (int q = 0; q < 4; ++q)
        GL16(hSrc + (long long)q * 16 * NN, hsDst0 + q * 4096);
    __syncthreads();

    int cur = 0;
    for (int jt = 0; jt < NN; jt += 128) {
        if (jt + 128 < NN) {
            if (cur == 0) {
                GL16(aSrc + jt + 128, tsDst1);
                #pragma unroll
                for (int q = 0; q < 4; ++q)
                    GL16(hSrc + (long long)q * 16 * NN + jt + 128, hsDst1 + q * 4096);
            } else {
                GL16(aSrc + jt + 128, tsDst0);
                #pragma unroll
                for (int q = 0; q < 4; ++q)
                    GL16(hSrc + (long long)q * 16 * NN + jt + 128, hsDst0 + q * 4096);
            }
        }
        const char* tsB = (const char*)&Ts[cur][0];
        const char* hsB = (const char*)&Hs[cur][0];
        int hr = w * 16 + r;
        #pragma unroll
        for (int kk = 0; kk < 4; ++kk) {
            int xo = kk * 64 + kg * 16;
            short8 a = *(const short8*)(tsB + r * 256 + (xo ^ ((r & 7) << 4)));
            short8 bb = *(const short8*)(hsB + hr * 256 + (xo ^ ((r & 7) << 4)));
            acc = __builtin_amdgcn_mfma_f32_16x16x32_bf16(a, bb, acc, 0, 0, 0);
        }
        __syncthreads();
        cur ^= 1;
    }

    int f = w * 16 + r;
    float bv = bias[f];
    #pragma unroll
    for (int rr = 0; rr < 4; ++rr) {
        long long gi = (long long)(i0 + kg * 4 + rr) * 64 + f;
        float v = acc[rr] + bv;
        if (FINAL) v = 0.5f * (U1[gi] + v);
        Y[gi] = v;
    }
}

// ---------------------------------------------------------------------------
extern "C" void kernel_launch(void* const* d_in, const int* in_sizes, int n_in,
                              void* d_out, int out_size, void* d_ws, size_t ws_size,
                              hipStream_t stream) {
    const float* A    = (const float*)d_in[0];
    const float* feat = (const float*)d_in[1];
    const float* wb   = (const float*)d_in[2];
    const float* W1   = (const float*)d_in[3];
    const float* b1   = (const float*)d_in[4];
    const float* W2   = (const float*)d_in[5];
    const float* b2   = (const float*)d_in[6];
    float* out = (float*)d_out;

    const size_t szS = (size_t)NN * NN * 2;       // 128 MB bf16 S
    const size_t szH = (size_t)64 * NN * 2;       // 1 MB  bf16 Ht
    char* p = (char*)d_ws;
    unsigned short* S   = (unsigned short*)p;
    unsigned short* H1t = (unsigned short*)(p + szS);
    unsigned short* H2t = (unsigned short*)(p + szS + szH);
    float*          U1  = (float*)(p + szS + 2 * szH);

    k_sym_build<<<8256, 256, 0, stream>>>(A, wb, S);
    k_small_gemm_t<<<128, 256, 0, stream>>>(feat, W1, H1t);
    k_gemm_skinny<0><<<512, 256, 0, stream>>>(S, H1t, b1, nullptr, U1);
    k_small_gemm_t<<<128, 256, 0, stream>>>(U1, W2, H2t);
    k_gemm_skinny<1><<<512, 256, 0, stream>>>(S, H2t, b2, U1, out);
}

// Round 7
// 458.123 us; speedup vs baseline: 1.0842x; 1.0842x over previous
//
#include <hip/hip_runtime.h>
#include <hip/hip_bf16.h>

// MHGCN: out = 0.5*(U1+U2), U1 = S@H1+b1 (H1=feat@W1), U2 = S@H2+b2 (H2=U1@W2)
// S = temp + temp^T, temp = einsum('ijk,kl->ij', A_stack, weight_b). N=8192.
//
//  1) k_small_gemm_t: H1t = (feat@W1)^T bf16 [64][N]
//  2) memset U1raw = 0
//  3) k_sym_fused: per 64x64 tile pair: S tiles (bf16, global) AND
//     U1raw[bi] += Stile@H1[bj], U1raw[bj] += Stile^T@H1[bi]  (f32 atomics)
//     -> pass-1 GEMM eliminated (fused while the tile is LDS-resident)
//  4) k_small_gemm_t (+b1 folded): H2t = ((U1raw+b1)@W2)^T
//  5) k_gemm_skinny: out = 0.5*(U1raw + b1 + S@H2 + b2)

#define NN 8192

typedef __attribute__((ext_vector_type(8))) short short8;
typedef __attribute__((ext_vector_type(8))) unsigned short u16x8;
typedef __attribute__((ext_vector_type(4))) unsigned short u16x4;
typedef __attribute__((ext_vector_type(4))) float f32x4;

static __device__ __forceinline__ unsigned short f2bf(float f) {
    unsigned u = __float_as_uint(f);
    u += 0x7FFFu + ((u >> 16) & 1u);     // round-to-nearest-even
    return (unsigned short)(u >> 16);
}

#define GL16(gsrc, ldst) __builtin_amdgcn_global_load_lds( \
    (const __attribute__((address_space(1))) void*)(gsrc), \
    (__attribute__((address_space(3))) void*)(ldst), 16, 0, 0)

// ---------------------------------------------------------------------------
// 1) S = temp+temp^T (bf16) + fused U1 partial accumulation.
//    Phase A (as R3-quad): tile1 -> regs, tile2 -> Tt (f32 row-major).
//    Phase B: sv = t1 + Tt^T -> S main tile + Sb (bf16 [64][72] row-major).
//    Phase C: mirror S tile from Sb transposed.
//    Phase D: MFMA — U1[bi-rows] += Sb @ H1t(bj cols);
//                    U1[bj-rows] += Sb^T @ H1t(bi cols)  [skip if bi==bj]
// ---------------------------------------------------------------------------
__global__ __launch_bounds__(256) void k_sym_fused(
        const float* __restrict__ A, const float* __restrict__ wb,
        const unsigned short* __restrict__ H1t,   // [64][NN] bf16
        unsigned short* __restrict__ S,
        float* __restrict__ U1) {                 // [NN][64] f32, pre-zeroed
    __shared__ float Tt[64 * 65];                 // tile2 f32, row-major
    __shared__ unsigned short Sb[64 * 72];        // S tile bf16, 16B-aligned rows

    int b = blockIdx.x;
    double disc = 66049.0 - 8.0 * (double)b;
    int bi = (int)((257.0 - sqrt(disc)) * 0.5);
    if (bi < 0) bi = 0; if (bi > 127) bi = 127;
    while (bi < 127 && (bi + 1) * (257 - (bi + 1)) / 2 <= b) ++bi;
    while (bi > 0 && bi * (257 - bi) / 2 > b) --bi;
    int bj = bi + (b - bi * (257 - bi) / 2);

    const float w0 = wb[0], w1 = wb[1], w2 = wb[2], w3 = wb[3], w4 = wb[4];
    int t = threadIdx.x;
    int qc = t & 15;          // quad-col
    int r0 = t >> 4;          // row base

    float t1[4][4];
    #pragma unroll
    for (int e = 0; e < 4; ++e) {
        int r = r0 + 16 * e;
        {   // tile1: (bi,bj)
            const f32x4* p = (const f32x4*)(A +
                ((long long)(bi * 64 + r) * NN + bj * 64 + 4 * qc) * 5);
            f32x4 f0 = p[0], f1 = p[1], f2 = p[2], f3 = p[3], f4 = p[4];
            t1[e][0] = f0[0]*w0 + f0[1]*w1 + f0[2]*w2 + f0[3]*w3 + f1[0]*w4;
            t1[e][1] = f1[1]*w0 + f1[2]*w1 + f1[3]*w2 + f2[0]*w3 + f2[1]*w4;
            t1[e][2] = f2[2]*w0 + f2[3]*w1 + f3[0]*w2 + f3[1]*w3 + f3[2]*w4;
            t1[e][3] = f3[3]*w0 + f4[0]*w1 + f4[1]*w2 + f4[2]*w3 + f4[3]*w4;
        }
        {   // tile2: (bj,bi) row-major into Tt
            const f32x4* p = (const f32x4*)(A +
                ((long long)(bj * 64 + r) * NN + bi * 64 + 4 * qc) * 5);
            f32x4 f0 = p[0], f1 = p[1], f2 = p[2], f3 = p[3], f4 = p[4];
            Tt[r * 65 + 4*qc + 0] = f0[0]*w0 + f0[1]*w1 + f0[2]*w2 + f0[3]*w3 + f1[0]*w4;
            Tt[r * 65 + 4*qc + 1] = f1[1]*w0 + f1[2]*w1 + f1[3]*w2 + f2[0]*w3 + f2[1]*w4;
            Tt[r * 65 + 4*qc + 2] = f2[2]*w0 + f2[3]*w1 + f3[0]*w2 + f3[1]*w3 + f3[2]*w4;
            Tt[r * 65 + 4*qc + 3] = f3[3]*w0 + f4[0]*w1 + f4[1]*w2 + f4[2]*w3 + f4[3]*w4;
        }
    }
    __syncthreads();
    #pragma unroll
    for (int e = 0; e < 4; ++e) {
        int r = r0 + 16 * e;
        u16x4 o;
        #pragma unroll
        for (int q = 0; q < 4; ++q) {
            float v = t1[e][q] + Tt[(4*qc + q) * 65 + r];   // Stile[r][4qc+q]
            o[q] = f2bf(v);
        }
        *(u16x4*)(S + (long long)(bi * 64 + r) * NN + bj * 64 + 4 * qc) = o;
        *(u16x4*)(&Sb[r * 72 + 4 * qc]) = o;
    }
    __syncthreads();                               // Sb complete

    // Phase C: mirror global tile S[bj..][bi..][i][j] = Sb[j][i]
    if (bi != bj) {
        #pragma unroll
        for (int e = 0; e < 2; ++e) {
            int i = (t >> 3) + 32 * e;
            int j0 = (t & 7) * 8;
            u16x8 o;
            #pragma unroll
            for (int q = 0; q < 8; ++q) o[q] = Sb[(j0 + q) * 72 + i];
            *(u16x8*)(S + (long long)(bj * 64 + i) * NN + bi * 64 + j0) = o;
        }
    }

    // Phase D: fused U1 accumulation. wave w owns m-rows [w*16, w*16+16).
    int lane = t & 63, w = t >> 6;
    int r = lane & 15, kg = lane >> 4;
    {   // P1: U1[bi*64 + m] += sum_k Sb[m][k] * H1[bj*64+k][n]
        f32x4 acc[4] = {{0,0,0,0},{0,0,0,0},{0,0,0,0},{0,0,0,0}};
        #pragma unroll
        for (int kk = 0; kk < 2; ++kk) {
            short8 a = *(const short8*)(&Sb[(w * 16 + r) * 72 + kk * 32 + kg * 8]);
            #pragma unroll
            for (int nt = 0; nt < 4; ++nt) {
                short8 bb = *(const short8*)(H1t +
                    (long long)(nt * 16 + r) * NN + bj * 64 + kk * 32 + kg * 8);
                acc[nt] = __builtin_amdgcn_mfma_f32_16x16x32_bf16(a, bb, acc[nt], 0, 0, 0);
            }
        }
        #pragma unroll
        for (int nt = 0; nt < 4; ++nt)
            #pragma unroll
            for (int rr = 0; rr < 4; ++rr)
                atomicAdd(U1 + (long long)(bi * 64 + w * 16 + kg * 4 + rr) * 64
                             + nt * 16 + r, acc[nt][rr]);
    }
    if (bi != bj) {   // P2: U1[bj*64 + m] += sum_k Sb[k][m] * H1[bi*64+k][n]
        f32x4 acc[4] = {{0,0,0,0},{0,0,0,0},{0,0,0,0},{0,0,0,0}};
        #pragma unroll
        for (int kk = 0; kk < 2; ++kk) {
            short8 a;
            #pragma unroll
            for (int j = 0; j < 8; ++j)
                a[j] = (short)Sb[(kk * 32 + kg * 8 + j) * 72 + w * 16 + r];
            #pragma unroll
            for (int nt = 0; nt < 4; ++nt) {
                short8 bb = *(const short8*)(H1t +
                    (long long)(nt * 16 + r) * NN + bi * 64 + kk * 32 + kg * 8);
                acc[nt] = __builtin_amdgcn_mfma_f32_16x16x32_bf16(a, bb, acc[nt], 0, 0, 0);
            }
        }
        #pragma unroll
        for (int nt = 0; nt < 4; ++nt)
            #pragma unroll
            for (int rr = 0; rr < 4; ++rr)
                atomicAdd(U1 + (long long)(bj * 64 + w * 16 + kg * 4 + rr) * 64
                             + nt * 16 + r, acc[nt][rr]);
    }
}

// ---------------------------------------------------------------------------
// 2/4) Yt[c][row] = sum_k (X[row][k]+bias[k]) * W[k][c]  (bias nullable)
//      bias folded as bw[c] = sum_k bias[k] W[k][c].
// ---------------------------------------------------------------------------
__global__ __launch_bounds__(256) void k_small_gemm_t(
        const float* __restrict__ X, const float* __restrict__ W,
        const float* __restrict__ bias,
        unsigned short* __restrict__ Yt) {
    __shared__ float Ys[64 * 65];
    int t = threadIdx.x, lane = t & 63, w = t >> 6;
    float wcol[64];
    #pragma unroll
    for (int k = 0; k < 64; ++k) wcol[k] = W[k * 64 + lane];
    float bw = 0.f;
    if (bias) {
        #pragma unroll
        for (int k = 0; k < 64; ++k) bw += bias[k] * wcol[k];
    }
    int r0 = blockIdx.x * 64;
    for (int rr = 0; rr < 16; ++rr) {
        const f32x4* x = (const f32x4*)(X + (long long)(r0 + w * 16 + rr) * 64);
        float acc = bw;
        #pragma unroll
        for (int k4 = 0; k4 < 16; ++k4) {
            f32x4 xv = x[k4];
            acc += xv[0]*wcol[4*k4] + xv[1]*wcol[4*k4+1]
                 + xv[2]*wcol[4*k4+2] + xv[3]*wcol[4*k4+3];
        }
        Ys[lane * 65 + w * 16 + rr] = acc;    // Ys[col][row-in-tile]
    }
    __syncthreads();
    int c = t >> 2, j0 = (t & 3) * 16;
    u16x8 o0, o1;
    #pragma unroll
    for (int q = 0; q < 8; ++q) {
        o0[q] = f2bf(Ys[c * 65 + j0 + q]);
        o1[q] = f2bf(Ys[c * 65 + j0 + 8 + q]);
    }
    *(u16x8*)(Yt + (long long)c * NN + r0 + j0) = o0;
    *(u16x8*)(Yt + (long long)c * NN + r0 + j0 + 8) = o1;
}

// ---------------------------------------------------------------------------
// 5) out[i][f] = 0.5*(U1raw[i][f] + b1[f] + (sum_j S[i][j]H2[j][f]) + b2[f])
//   global_load_lds dbuf MFMA (R3 structure).
// ---------------------------------------------------------------------------
__global__ __launch_bounds__(256) void k_gemm_final(
        const unsigned short* __restrict__ S,
        const unsigned short* __restrict__ Ht,   // [64][NN]
        const float* __restrict__ b1,
        const float* __restrict__ b2,
        const float* __restrict__ U1,            // raw (no bias)
        float* __restrict__ Y) {
    __shared__ unsigned short Ts[2][16 * 128];   // 2 x 4 KB
    __shared__ unsigned short Hs[2][64 * 128];   // 2 x 16 KB
    int t = threadIdx.x, lane = t & 63, w = t >> 6;
    int i0 = blockIdx.x * 16;
    int r = lane & 15, kg = lane >> 4;

    int srow = t >> 4, sc = t & 15;
    int sbyte = (sc * 16) ^ ((srow & 7) << 4);
    const unsigned short* aSrc = S + (long long)(i0 + srow) * NN + (sbyte >> 1);
    const unsigned short* hSrc = Ht + (long long)srow * NN + (sbyte >> 1);
    char* tsDst0 = (char*)&Ts[0][0] + t * 16;
    char* tsDst1 = (char*)&Ts[1][0] + t * 16;
    char* hsDst0 = (char*)&Hs[0][0] + t * 16;
    char* hsDst1 = (char*)&Hs[1][0] + t * 16;

    f32x4 acc = {0.f, 0.f, 0.f, 0.f};

    GL16(aSrc, tsDst0);
    #pragma unroll
    for (int q = 0; q < 4; ++q)
        GL16(hSrc + (long long)q * 16 * NN, hsDst0 + q * 4096);
    __syncthreads();

    int cur = 0;
    for (int jt = 0; jt < NN; jt += 128) {
        if (jt + 128 < NN) {
            if (cur == 0) {
                GL16(aSrc + jt + 128, tsDst1);
                #pragma unroll
                for (int q = 0; q < 4; ++q)
                    GL16(hSrc + (long long)q * 16 * NN + jt + 128, hsDst1 + q * 4096);
            } else {
                GL16(aSrc + jt + 128, tsDst0);
                #pragma unroll
                for (int q = 0; q < 4; ++q)
                    GL16(hSrc + (long long)q * 16 * NN + jt + 128, hsDst0 + q * 4096);
            }
        }
        const char* tsB = (const char*)&Ts[cur][0];
        const char* hsB = (const char*)&Hs[cur][0];
        int hr = w * 16 + r;
        #pragma unroll
        for (int kk = 0; kk < 4; ++kk) {
            int xo = kk * 64 + kg * 16;
            short8 a = *(const short8*)(tsB + r * 256 + (xo ^ ((r & 7) << 4)));
            short8 bb = *(const short8*)(hsB + hr * 256 + (xo ^ ((r & 7) << 4)));
            acc = __builtin_amdgcn_mfma_f32_16x16x32_bf16(a, bb, acc, 0, 0, 0);
        }
        __syncthreads();
        cur ^= 1;
    }

    int f = w * 16 + r;
    float bv = b1[f] + b2[f];
    #pragma unroll
    for (int rr = 0; rr < 4; ++rr) {
        long long gi = (long long)(i0 + kg * 4 + rr) * 64 + f;
        Y[gi] = 0.5f * (U1[gi] + acc[rr] + bv);
    }
}

// ---------------------------------------------------------------------------
extern "C" void kernel_launch(void* const* d_in, const int* in_sizes, int n_in,
                              void* d_out, int out_size, void* d_ws, size_t ws_size,
                              hipStream_t stream) {
    const float* A    = (const float*)d_in[0];
    const float* feat = (const float*)d_in[1];
    const float* wb   = (const float*)d_in[2];
    const float* W1   = (const float*)d_in[3];
    const float* b1   = (const float*)d_in[4];
    const float* W2   = (const float*)d_in[5];
    const float* b2   = (const float*)d_in[6];
    float* out = (float*)d_out;

    const size_t szS = (size_t)NN * NN * 2;       // 128 MB bf16 S
    const size_t szH = (size_t)64 * NN * 2;       // 1 MB  bf16 Ht
    const size_t szU = (size_t)NN * 64 * 4;       // 2 MB  f32  U1raw
    char* p = (char*)d_ws;
    unsigned short* S   = (unsigned short*)p;
    unsigned short* H1t = (unsigned short*)(p + szS);
    unsigned short* H2t = (unsigned short*)(p + szS + szH);
    float*          U1  = (float*)(p + szS + 2 * szH);

    k_small_gemm_t<<<128, 256, 0, stream>>>(feat, W1, nullptr, H1t);
    hipMemsetAsync(U1, 0, szU, stream);
    k_sym_fused<<<8256, 256, 0, stream>>>(A, wb, H1t, S, U1);
    k_small_gemm_t<<<128, 256, 0, stream>>>(U1, W2, b1, H2t);
    k_gemm_final<<<512, 256, 0, stream>>>(S, H2t, b1, b2, U1, out);
}

// Round 8
// 425.313 us; speedup vs baseline: 1.1678x; 1.0771x over previous
//
#include <hip/hip_runtime.h>
#include <hip/hip_bf16.h>

// MHGCN: out = 0.5*(U1+U2), U1 = S@(feat@W1)+b1, U2 = S@(U1@W2)+b2,
// S = temp + temp^T, temp = einsum('ijk,kl->ij', A_stack, weight_b). N=8192.
//
//  1) k_sym_build: A_stack -> S bf16. A staged via global_load_lds width-16
//     (each 64B line touched EXACTLY once, async, no VGPR round-trip);
//     stride-5 redistribution done from LDS (2-way bank alias = free).
//     R3's 5x dwordx4-at-stride-80B touched each line ~5x (suspected
//     TA/L1 line-throughput bound -> ~60% efficiency).
//  2) k_small_gemm_t: feature@W1 -> H1t bf16 [64][N]
//  3) k_gemm_skinny<0>: U1 = S@H1 + b1 (R3 structure, verbatim)
//  4) k_small_gemm_t: U1@W2 -> H2t
//  5) k_gemm_skinny<1>: out = 0.5*(U1 + S@H2 + b2)

#define NN 8192

typedef __attribute__((ext_vector_type(8))) short short8;
typedef __attribute__((ext_vector_type(8))) unsigned short u16x8;
typedef __attribute__((ext_vector_type(4))) unsigned short u16x4;
typedef __attribute__((ext_vector_type(4))) float f32x4;

static __device__ __forceinline__ unsigned short f2bf(float f) {
    unsigned u = __float_as_uint(f);
    u += 0x7FFFu + ((u >> 16) & 1u);     // round-to-nearest-even
    return (unsigned short)(u >> 16);
}

#define GL16(gsrc, ldst) __builtin_amdgcn_global_load_lds( \
    (const __attribute__((address_space(1))) void*)(gsrc), \
    (__attribute__((address_space(3))) void*)(ldst), 16, 0, 0)

// ---------------------------------------------------------------------------
// 1) S = temp + temp^T (bf16). Upper-tri 64x64 tile pairs; A read exactly once
//    with dense GL16 staging (16 rows = 20480B per batch, 5 chunks/thread).
//    Compute: element (r,j) reads Raw[r*320 + 5j .. +4] (stride-5 = 2-way
//    bank alias, free), tv -> T1s row-major / T2t transposed. Output = R5
//    phases (full 64-row coverage).
// ---------------------------------------------------------------------------
__global__ __launch_bounds__(256) void k_sym_build(
        const float* __restrict__ A, const float* __restrict__ wb,
        unsigned short* __restrict__ S) {
    __shared__ float Raw[16 * 320];      // 20 KB staging (16 rows x 320 f32)
    __shared__ float T1s[64 * 65];       // temp1 row-major
    __shared__ float T2t[64 * 65];       // temp2 transposed

    int b = blockIdx.x;
    double disc = 66049.0 - 8.0 * (double)b;
    int bi = (int)((257.0 - sqrt(disc)) * 0.5);
    if (bi < 0) bi = 0; if (bi > 127) bi = 127;
    while (bi < 127 && (bi + 1) * (257 - (bi + 1)) / 2 <= b) ++bi;
    while (bi > 0 && bi * (257 - bi) / 2 > b) --bi;
    int bj = bi + (b - bi * (257 - bi) / 2);

    const float w0 = wb[0], w1 = wb[1], w2 = wb[2], w3 = wb[3], w4 = wb[4];
    int t = threadIdx.x;

    // staging decode: chunk q of thread t covers Raw bytes o = t*16 + q*4096
    int srow[5], srem[5];                // row in batch, float offset in row
    #pragma unroll
    for (int q = 0; q < 5; ++q) {
        int o = t * 16 + q * 4096;       // byte offset in 20480B batch
        srow[q] = o / 1280;              // row (0..15)
        srem[q] = (o % 1280) >> 2;       // float offset in row (0..316)
    }
    int cr = t >> 4;                     // compute: row in batch
    int cj = t & 15;                     // col base (cols cj, cj+16, +32, +48)

    #pragma unroll
    for (int half = 0; half < 2; ++half) {
        int tr = half == 0 ? bi : bj;    // tile row-base in A
        int tc = half == 0 ? bj : bi;    // tile col-base
        for (int batch = 0; batch < 4; ++batch) {
            // stage 16 rows via GL16 (dest linear t*16 + q*4096)
            #pragma unroll
            for (int q = 0; q < 5; ++q) {
                const float* src = A +
                    ((long long)(tr * 64 + batch * 16 + srow[q]) * NN + tc * 64) * 5
                    + srem[q];
                GL16(src, (char*)Raw + t * 16 + q * 4096);
            }
            __syncthreads();             // drains vmcnt + lgkm (staging visible)
            #pragma unroll
            for (int e = 0; e < 4; ++e) {
                int j = cj + 16 * e;
                const float* p = &Raw[cr * 320 + 5 * j];
                float tv = p[0]*w0 + p[1]*w1 + p[2]*w2 + p[3]*w3 + p[4]*w4;
                int gr = batch * 16 + cr;
                if (half == 0) T1s[gr * 65 + j] = tv;
                else           T2t[j * 65 + gr] = tv;
            }
            __syncthreads();             // Raw reusable
        }
    }

    // Phase B: main tile  S[bi..][bj..][i][j] = T1s[i][j] + T2t[i][j]
    #pragma unroll
    for (int e = 0; e < 2; ++e) {
        int i = (t >> 3) + 32 * e;
        int j0 = (t & 7) * 8;
        u16x8 o;
        #pragma unroll
        for (int q = 0; q < 8; ++q)
            o[q] = f2bf(T1s[i * 65 + j0 + q] + T2t[i * 65 + j0 + q]);
        *(u16x8*)(S + (long long)(bi * 64 + i) * NN + bj * 64 + j0) = o;
    }
    // Phase C: mirror tile S[bj..][bi..][i][j] = tile[j][i]
    if (bi != bj) {
        #pragma unroll
        for (int e = 0; e < 2; ++e) {
            int i = (t >> 3) + 32 * e;
            int j0 = (t & 7) * 8;
            u16x8 o;
            #pragma unroll
            for (int q = 0; q < 8; ++q)
                o[q] = f2bf(T1s[(j0 + q) * 65 + i] + T2t[(j0 + q) * 65 + i]);
            *(u16x8*)(S + (long long)(bj * 64 + i) * NN + bi * 64 + j0) = o;
        }
    }
}

// ---------------------------------------------------------------------------
// 2/4) Yt[c][row] = sum_k X[row][k]*W[k][c]   (bf16, transposed output)
// ---------------------------------------------------------------------------
__global__ __launch_bounds__(256) void k_small_gemm_t(
        const float* __restrict__ X, const float* __restrict__ W,
        unsigned short* __restrict__ Yt) {
    __shared__ float Ys[64 * 65];
    int t = threadIdx.x, lane = t & 63, w = t >> 6;
    float wcol[64];
    #pragma unroll
    for (int k = 0; k < 64; ++k) wcol[k] = W[k * 64 + lane];
    int r0 = blockIdx.x * 64;
    for (int rr = 0; rr < 16; ++rr) {
        const f32x4* x = (const f32x4*)(X + (long long)(r0 + w * 16 + rr) * 64);
        float acc = 0.f;
        #pragma unroll
        for (int k4 = 0; k4 < 16; ++k4) {
            f32x4 xv = x[k4];
            acc += xv[0]*wcol[4*k4] + xv[1]*wcol[4*k4+1]
                 + xv[2]*wcol[4*k4+2] + xv[3]*wcol[4*k4+3];
        }
        Ys[lane * 65 + w * 16 + rr] = acc;    // Ys[col][row-in-tile]
    }
    __syncthreads();
    int c = t >> 2, j0 = (t & 3) * 16;
    u16x8 o0, o1;
    #pragma unroll
    for (int q = 0; q < 8; ++q) {
        o0[q] = f2bf(Ys[c * 65 + j0 + q]);
        o1[q] = f2bf(Ys[c * 65 + j0 + 8 + q]);
    }
    *(u16x8*)(Yt + (long long)c * NN + r0 + j0) = o0;
    *(u16x8*)(Yt + (long long)c * NN + r0 + j0 + 8) = o1;
}

// ---------------------------------------------------------------------------
// 3/5) Y[i][f] = (FINAL? 0.5*(U1+.) : .)(bias[f] + sum_j S[i][j]*H[j][f])
//   global_load_lds dbuf MFMA; pre-swizzled global source, XOR ds_read.
// ---------------------------------------------------------------------------
template<int FINAL>
__global__ __launch_bounds__(256) void k_gemm_skinny(
        const unsigned short* __restrict__ S,
        const unsigned short* __restrict__ Ht,   // [64][NN]
        const float* __restrict__ bias,
        const float* __restrict__ U1,
        float* __restrict__ Y) {
    __shared__ unsigned short Ts[2][16 * 128];   // 2 x 4 KB
    __shared__ unsigned short Hs[2][64 * 128];   // 2 x 16 KB
    int t = threadIdx.x, lane = t & 63, w = t >> 6;
    int i0 = blockIdx.x * 16;
    int r = lane & 15, kg = lane >> 4;

    int srow = t >> 4, sc = t & 15;
    int sbyte = (sc * 16) ^ ((srow & 7) << 4);
    const unsigned short* aSrc = S + (long long)(i0 + srow) * NN + (sbyte >> 1);
    const unsigned short* hSrc = Ht + (long long)srow * NN + (sbyte >> 1);
    char* tsDst0 = (char*)&Ts[0][0] + t * 16;
    char* tsDst1 = (char*)&Ts[1][0] + t * 16;
    char* hsDst0 = (char*)&Hs[0][0] + t * 16;
    char* hsDst1 = (char*)&Hs[1][0] + t * 16;

    f32x4 acc = {0.f, 0.f, 0.f, 0.f};

    GL16(aSrc, tsDst0);
    #pragma unroll
    for (int q = 0; q < 4; ++q)
        GL16(hSrc + (long long)q * 16 * NN, hsDst0 + q * 4096);
    __syncthreads();

    int cur = 0;
    for (int jt = 0; jt < NN; jt += 128) {
        if (jt + 128 < NN) {
            if (cur == 0) {
                GL16(aSrc + jt + 128, tsDst1);
                #pragma unroll
                for (int q = 0; q < 4; ++q)
                    GL16(hSrc + (long long)q * 16 * NN + jt + 128, hsDst1 + q * 4096);
            } else {
                GL16(aSrc + jt + 128, tsDst0);
                #pragma unroll
                for (int q = 0; q < 4; ++q)
                    GL16(hSrc + (long long)q * 16 * NN + jt + 128, hsDst0 + q * 4096);
            }
        }
        const char* tsB = (const char*)&Ts[cur][0];
        const char* hsB = (const char*)&Hs[cur][0];
        int hr = w * 16 + r;
        #pragma unroll
        for (int kk = 0; kk < 4; ++kk) {
            int xo = kk * 64 + kg * 16;
            short8 a = *(const short8*)(tsB + r * 256 + (xo ^ ((r & 7) << 4)));
            short8 bb = *(const short8*)(hsB + hr * 256 + (xo ^ ((r & 7) << 4)));
            acc = __builtin_amdgcn_mfma_f32_16x16x32_bf16(a, bb, acc, 0, 0, 0);
        }
        __syncthreads();
        cur ^= 1;
    }

    int f = w * 16 + r;
    float bv = bias[f];
    #pragma unroll
    for (int rr = 0; rr < 4; ++rr) {
        long long gi = (long long)(i0 + kg * 4 + rr) * 64 + f;
        float v = acc[rr] + bv;
        if (FINAL) v = 0.5f * (U1[gi] + v);
        Y[gi] = v;
    }
}

// ---------------------------------------------------------------------------
extern "C" void kernel_launch(void* const* d_in, const int* in_sizes, int n_in,
                              void* d_out, int out_size, void* d_ws, size_t ws_size,
                              hipStream_t stream) {
    const float* A    = (const float*)d_in[0];
    const float* feat = (const float*)d_in[1];
    const float* wb   = (const float*)d_in[2];
    const float* W1   = (const float*)d_in[3];
    const float* b1   = (const float*)d_in[4];
    const float* W2   = (const float*)d_in[5];
    const float* b2   = (const float*)d_in[6];
    float* out = (float*)d_out;

    const size_t szS = (size_t)NN * NN * 2;       // 128 MB bf16 S
    const size_t szH = (size_t)64 * NN * 2;       // 1 MB  bf16 Ht
    char* p = (char*)d_ws;
    unsigned short* S   = (unsigned short*)p;
    unsigned short* H1t = (unsigned short*)(p + szS);
    unsigned short* H2t = (unsigned short*)(p + szS + szH);
    float*          U1  = (float*)(p + szS + 2 * szH);

    k_sym_build<<<8256, 256, 0, stream>>>(A, wb, S);
    k_small_gemm_t<<<128, 256, 0, stream>>>(feat, W1, H1t);
    k_gemm_skinny<0><<<512, 256, 0, stream>>>(S, H1t, b1, nullptr, U1);
    k_small_gemm_t<<<128, 256, 0, stream>>>(U1, W2, H2t);
    k_gemm_skinny<1><<<512, 256, 0, stream>>>(S, H2t, b2, U1, out);
}